// Round 1
// baseline (6754.134 us; speedup 1.0000x reference)
//
#include <hip/hip_runtime.h>

#define N_NODES 100000

// ---------------- dtype detection ----------------
// edge_index values are in [0, 100000) (< 2^31). If the buffer is int64
// little-endian, every odd 32-bit word (high half) is 0. If int32, odd words
// are random indices -> OR over 2048 of them is nonzero w.p. ~1.
__global__ void detect_i64_kernel(const unsigned int* __restrict__ e,
                                  unsigned int* __restrict__ flag) {
    int i = blockIdx.x * blockDim.x + threadIdx.x;  // 0..2047
    unsigned int v = e[2 * i + 1];
    if (v != 0u) atomicOr(flag, 1u);
}

__device__ __forceinline__ void load_edge(const void* eidx, unsigned int is_i32,
                                          long long i, long long E,
                                          int& s, int& d) {
    if (is_i32 == 0u) {
        const long long* p = (const long long*)eidx;
        s = (int)p[i];
        d = (int)p[E + i];
    } else {
        const int* p = (const int*)eidx;
        s = p[i];
        d = p[E + i];
    }
}

// ---------------- layer 1 scatter: agg1[dst] += x[src], F=5 ----------------
__global__ void scatter_f5_kernel(const void* __restrict__ eidx,
                                  const unsigned int* __restrict__ flag,
                                  const float* __restrict__ x,
                                  float* __restrict__ agg, long long E) {
    long long i = (long long)blockIdx.x * blockDim.x + threadIdx.x;
    if (i >= E) return;
    unsigned int is_i32 = *flag;
    int s, d;
    load_edge(eidx, is_i32, i, E, s, d);
    const float* xs = x + (long long)s * 5;
    float* a = agg + (long long)d * 5;
#pragma unroll
    for (int f = 0; f < 5; ++f) atomicAdd(&a[f], xs[f]);
}

// ---------------- layer 2 scatter: agg2[dst] += h[src], F=16 ----------------
__global__ void scatter_f16_kernel(const void* __restrict__ eidx,
                                   const unsigned int* __restrict__ flag,
                                   const float* __restrict__ h,
                                   float* __restrict__ agg, long long E) {
    long long i = (long long)blockIdx.x * blockDim.x + threadIdx.x;
    if (i >= E) return;
    unsigned int is_i32 = *flag;
    int s, d;
    load_edge(eidx, is_i32, i, E, s, d);
    const float4* hs = (const float4*)(h + (long long)s * 16);
    float* a = agg + (long long)d * 16;
#pragma unroll
    for (int q = 0; q < 4; ++q) {
        float4 v = hs[q];
        atomicAdd(&a[q * 4 + 0], v.x);
        atomicAdd(&a[q * 4 + 1], v.y);
        atomicAdd(&a[q * 4 + 2], v.z);
        atomicAdd(&a[q * 4 + 3], v.w);
    }
}

// ------------- MLP1: h = relu((x+agg1)@W1a + b1a)@W1b + b1b -------------
__global__ void mlp_5_16_kernel(const float* __restrict__ x,
                                const float* __restrict__ agg,
                                const float* __restrict__ W1,
                                const float* __restrict__ b1,
                                const float* __restrict__ W2,
                                const float* __restrict__ b2,
                                float* __restrict__ out, int N) {
    int n = blockIdx.x * blockDim.x + threadIdx.x;
    if (n >= N) return;
    float in[5];
#pragma unroll
    for (int f = 0; f < 5; ++f)
        in[f] = x[(long long)n * 5 + f] + agg[(long long)n * 5 + f];
    float hid[16];
#pragma unroll
    for (int j = 0; j < 16; ++j) {
        float acc = b1[j];
#pragma unroll
        for (int f = 0; f < 5; ++f) acc = fmaf(in[f], W1[f * 16 + j], acc);
        hid[j] = fmaxf(acc, 0.0f);
    }
#pragma unroll
    for (int j = 0; j < 16; ++j) {
        float acc = b2[j];
#pragma unroll
        for (int k = 0; k < 16; ++k) acc = fmaf(hid[k], W2[k * 16 + j], acc);
        out[(long long)n * 16 + j] = acc;
    }
}

// ------------- MLP2: out = relu((h+agg2)@W2a + b2a)@W2b + b2b -------------
__global__ void mlp_16_16_kernel(const float* __restrict__ h,
                                 const float* __restrict__ agg,
                                 const float* __restrict__ W1,
                                 const float* __restrict__ b1,
                                 const float* __restrict__ W2,
                                 const float* __restrict__ b2,
                                 float* __restrict__ out, int N) {
    int n = blockIdx.x * blockDim.x + threadIdx.x;
    if (n >= N) return;
    float in[16];
#pragma unroll
    for (int f = 0; f < 16; ++f)
        in[f] = h[(long long)n * 16 + f] + agg[(long long)n * 16 + f];
    float hid[16];
#pragma unroll
    for (int j = 0; j < 16; ++j) {
        float acc = b1[j];
#pragma unroll
        for (int f = 0; f < 16; ++f) acc = fmaf(in[f], W1[f * 16 + j], acc);
        hid[j] = fmaxf(acc, 0.0f);
    }
#pragma unroll
    for (int j = 0; j < 16; ++j) {
        float acc = b2[j];
#pragma unroll
        for (int k = 0; k < 16; ++k) acc = fmaf(hid[k], W2[k * 16 + j], acc);
        out[(long long)n * 16 + j] = acc;
    }
}

extern "C" void kernel_launch(void* const* d_in, const int* in_sizes, int n_in,
                              void* d_out, int out_size, void* d_ws, size_t ws_size,
                              hipStream_t stream) {
    const float* x    = (const float*)d_in[0];
    const void*  eidx = d_in[1];
    const float* W1a  = (const float*)d_in[2];
    const float* b1a  = (const float*)d_in[3];
    const float* W1b  = (const float*)d_in[4];
    const float* b1b  = (const float*)d_in[5];
    const float* W2a  = (const float*)d_in[6];
    const float* b2a  = (const float*)d_in[7];
    const float* W2b  = (const float*)d_in[8];
    const float* b2b  = (const float*)d_in[9];
    float* out = (float*)d_out;

    const long long E = (long long)in_sizes[1] / 2;
    const int N = N_NODES;

    // workspace layout (bytes)
    char* ws = (char*)d_ws;
    const size_t off_flag = 0;
    const size_t off_agg1 = 4096;                                // N*5 f32 = 2,000,000 B
    const size_t off_agg2 = off_agg1 + 2 * 1024 * 1024;          // N*16 f32 = 6,400,000 B
    const size_t off_h    = off_agg2 + 7 * 1024 * 1024;          // N*16 f32
    unsigned int* flag = (unsigned int*)(ws + off_flag);
    float* agg1 = (float*)(ws + off_agg1);
    float* agg2 = (float*)(ws + off_agg2);
    float* h    = (float*)(ws + off_h);

    // zero flag + agg1 + agg2 in one async memset (graph-capturable)
    hipMemsetAsync(ws, 0, off_agg2 + (size_t)N * 16 * sizeof(float), stream);

    // detect int64 vs int32 edge_index
    detect_i64_kernel<<<8, 256, 0, stream>>>((const unsigned int*)eidx, flag);

    // layer 1
    {
        int blocks = (int)((E + 255) / 256);
        scatter_f5_kernel<<<blocks, 256, 0, stream>>>(eidx, flag, x, agg1, E);
        mlp_5_16_kernel<<<(N + 255) / 256, 256, 0, stream>>>(x, agg1, W1a, b1a, W1b, b1b, h, N);
    }
    // layer 2
    {
        int blocks = (int)((E + 255) / 256);
        scatter_f16_kernel<<<blocks, 256, 0, stream>>>(eidx, flag, h, agg2, E);
        mlp_16_16_kernel<<<(N + 255) / 256, 256, 0, stream>>>(h, agg2, W2a, b2a, W2b, b2b, out, N);
    }
}

// Round 2
// 896.454 us; speedup vs baseline: 7.5343x; 7.5343x over previous
//
#include <hip/hip_runtime.h>

#define N_NODES   100000
#define BIN_NODES 1792
#define NBINS     56          // ceil(100000/1792)
#define NCHUNK    512
#define PS16      17          // padded LDS stride for F=16 (bank spread)

// ---------------- dtype detection ----------------
// edge_index values < 2^31. If int64 LE, every odd 32-bit word is 0.
__global__ void detect_i64_kernel(const unsigned int* __restrict__ e,
                                  unsigned int* __restrict__ flag) {
    int i = blockIdx.x * blockDim.x + threadIdx.x;  // 0..2047
    unsigned int v = e[2 * i + 1];
    if (v != 0u) atomicOr(flag, 1u);
}

// ---------------- pass 1: per-chunk histogram over dst bins ----------------
__global__ void count_kernel(const void* __restrict__ eidx,
                             const unsigned int* __restrict__ flag,
                             int* __restrict__ hist, int E) {
    __shared__ int lh[NBINS];
    int tid = threadIdx.x, c = blockIdx.x;
    for (int i = tid; i < NBINS; i += blockDim.x) lh[i] = 0;
    __syncthreads();
    int per = (E + NCHUNK - 1) / NCHUNK;
    int e0 = c * per, e1 = min(E, e0 + per);
    unsigned int is32 = *flag;
    for (int e = e0 + tid; e < e1; e += blockDim.x) {
        int d = is32 ? ((const int*)eidx)[E + e]
                     : (int)((const long long*)eidx)[E + e];
        atomicAdd(&lh[d / BIN_NODES], 1);
    }
    __syncthreads();
    for (int i = tid; i < NBINS; i += blockDim.x) hist[c * NBINS + i] = lh[i];
}

// ---------------- pass 2: scan -> bin starts + per-(chunk,bin) offsets ------
__global__ void scan_kernel(const int* __restrict__ hist,
                            int* __restrict__ off_rel,
                            int* __restrict__ bin_start) {
    __shared__ int totals[NBINS];
    int tid = threadIdx.x, wave = tid >> 6, lane = tid & 63;
    for (int b = wave; b < NBINS; b += 16) {
        int carry = 0;
        for (int k = 0; k < NCHUNK; k += 64) {
            int v = hist[(k + lane) * NBINS + b];
            int s = v;
            for (int off = 1; off < 64; off <<= 1) {
                int t = __shfl_up(s, off);
                if (lane >= off) s += t;
            }
            off_rel[(k + lane) * NBINS + b] = carry + s - v;   // exclusive
            carry += __shfl(s, 63);
        }
        if (lane == 0) totals[b] = carry;
    }
    __syncthreads();
    if (tid == 0) {
        int acc = 0;
        for (int b = 0; b < NBINS; ++b) { bin_start[b] = acc; acc += totals[b]; }
        bin_start[NBINS] = acc;
    }
}

// ---------------- pass 3: scatter edges into bin-sorted order ---------------
// packed edge: (dst_local << 17) | src   (src < 2^17, dst_local < 2048)
__global__ void scatter_kernel(const void* __restrict__ eidx,
                               const unsigned int* __restrict__ flag,
                               const int* __restrict__ off_rel,
                               const int* __restrict__ bin_start,
                               unsigned int* __restrict__ sorted, int E) {
    __shared__ int lcnt[NBINS];
    __shared__ int lbase[NBINS];
    int tid = threadIdx.x, c = blockIdx.x;
    for (int i = tid; i < NBINS; i += blockDim.x) {
        lcnt[i] = 0;
        lbase[i] = bin_start[i] + off_rel[c * NBINS + i];
    }
    __syncthreads();
    int per = (E + NCHUNK - 1) / NCHUNK;
    int e0 = c * per, e1 = min(E, e0 + per);
    unsigned int is32 = *flag;
    for (int e = e0 + tid; e < e1; e += blockDim.x) {
        int s, d;
        if (is32) {
            const int* p = (const int*)eidx; s = p[e]; d = p[E + e];
        } else {
            const long long* p = (const long long*)eidx; s = (int)p[e]; d = (int)p[E + e];
        }
        int b = d / BIN_NODES;
        int dl = d - b * BIN_NODES;
        int pos = lbase[b] + atomicAdd(&lcnt[b], 1);
        sorted[pos] = ((unsigned int)dl << 17) | (unsigned int)s;
    }
}

// ---------------- aggregation, F=16 (layer 2): LDS bin accumulate -----------
__global__ __launch_bounds__(1024) void agg16_kernel(
    const unsigned int* __restrict__ sorted, const int* __restrict__ bin_start,
    const float* __restrict__ h, float* __restrict__ partial, int S, int N) {
    __shared__ float lagg[BIN_NODES * PS16];
    int tid = threadIdx.x, s = blockIdx.x, bin = blockIdx.y;
    for (int i = tid; i < BIN_NODES * PS16; i += 1024) lagg[i] = 0.f;
    __syncthreads();
    int bs = bin_start[bin], be = bin_start[bin + 1];
    int cnt = be - bs, per = (cnt + S - 1) / S;
    int e0 = bs + s * per, e1 = min(be, e0 + per);
    int g = tid >> 4, f = tid & 15;          // 64 groups x 16 lanes
#pragma unroll 2
    for (int e = e0 + g; e < e1; e += 64) {
        unsigned int p = sorted[e];
        int src = p & 0x1FFFF, dl = p >> 17;
        atomicAdd(&lagg[dl * PS16 + f], h[src * 16 + f]);
    }
    __syncthreads();
    int base = bin * BIN_NODES;
    int bn = min(BIN_NODES, N - base);
    float* out = partial + (long long)s * N * 16;
    for (int i = tid; i < bn * 16; i += 1024) {
        int node = i >> 4, ff = i & 15;
        out[(long long)(base + node) * 16 + ff] = lagg[node * PS16 + ff];
    }
}

// ---------------- aggregation, F=5 (layer 1) --------------------------------
__global__ __launch_bounds__(1024) void agg5_kernel(
    const unsigned int* __restrict__ sorted, const int* __restrict__ bin_start,
    const float* __restrict__ x, float* __restrict__ partial, int S, int N) {
    __shared__ float lagg[BIN_NODES * 5];
    int tid = threadIdx.x, s = blockIdx.x, bin = blockIdx.y;
    for (int i = tid; i < BIN_NODES * 5; i += 1024) lagg[i] = 0.f;
    __syncthreads();
    int bs = bin_start[bin], be = bin_start[bin + 1];
    int cnt = be - bs, per = (cnt + S - 1) / S;
    int e0 = bs + s * per, e1 = min(be, e0 + per);
#pragma unroll 2
    for (int e = e0 + tid; e < e1; e += 1024) {
        unsigned int p = sorted[e];
        int src = p & 0x1FFFF, dl = p >> 17;
        const float* xs = x + (long long)src * 5;
#pragma unroll
        for (int f = 0; f < 5; ++f) atomicAdd(&lagg[dl * 5 + f], xs[f]);
    }
    __syncthreads();
    int base = bin * BIN_NODES;
    int bn = min(BIN_NODES, N - base);
    float* out = partial + (long long)s * N * 5;
    for (int i = tid; i < bn * 5; i += 1024) out[(long long)base * 5 + i] = lagg[i];
}

// ---------- fallback atomic scatters (used only if ws too small) ------------
__device__ __forceinline__ void load_edge(const void* eidx, unsigned int is32,
                                          int i, int E, int& s, int& d) {
    if (is32 == 0u) {
        const long long* p = (const long long*)eidx;
        s = (int)p[i]; d = (int)p[E + i];
    } else {
        const int* p = (const int*)eidx;
        s = p[i]; d = p[E + i];
    }
}

__global__ void scatter_f5_kernel(const void* __restrict__ eidx,
                                  const unsigned int* __restrict__ flag,
                                  const float* __restrict__ x,
                                  float* __restrict__ agg, int E) {
    int i = blockIdx.x * blockDim.x + threadIdx.x;
    if (i >= E) return;
    int s, d; load_edge(eidx, *flag, i, E, s, d);
    const float* xs = x + (long long)s * 5;
    float* a = agg + (long long)d * 5;
#pragma unroll
    for (int f = 0; f < 5; ++f) atomicAdd(&a[f], xs[f]);
}

__global__ void scatter_f16_kernel(const void* __restrict__ eidx,
                                   const unsigned int* __restrict__ flag,
                                   const float* __restrict__ h,
                                   float* __restrict__ agg, int E) {
    int i = blockIdx.x * blockDim.x + threadIdx.x;
    if (i >= E) return;
    int s, d; load_edge(eidx, *flag, i, E, s, d);
    const float* hs = h + (long long)s * 16;
    float* a = agg + (long long)d * 16;
#pragma unroll
    for (int f = 0; f < 16; ++f) atomicAdd(&a[f], hs[f]);
}

// ------------- MLP1: h = relu((x+sum partials)@W1a+b1a)@W1b+b1b -------------
__global__ void mlp1_kernel(const float* __restrict__ x,
                            const float* __restrict__ partial, int S,
                            const float* __restrict__ W1, const float* __restrict__ b1,
                            const float* __restrict__ W2, const float* __restrict__ b2,
                            float* __restrict__ out, int N) {
    int n = blockIdx.x * blockDim.x + threadIdx.x;
    if (n >= N) return;
    float in[5];
#pragma unroll
    for (int f = 0; f < 5; ++f) in[f] = x[(long long)n * 5 + f];
    for (int s = 0; s < S; ++s) {
        const float* p = partial + (long long)s * N * 5 + (long long)n * 5;
#pragma unroll
        for (int f = 0; f < 5; ++f) in[f] += p[f];
    }
    float hid[16];
#pragma unroll
    for (int j = 0; j < 16; ++j) {
        float acc = b1[j];
#pragma unroll
        for (int f = 0; f < 5; ++f) acc = fmaf(in[f], W1[f * 16 + j], acc);
        hid[j] = fmaxf(acc, 0.0f);
    }
#pragma unroll
    for (int j = 0; j < 16; ++j) {
        float acc = b2[j];
#pragma unroll
        for (int k = 0; k < 16; ++k) acc = fmaf(hid[k], W2[k * 16 + j], acc);
        out[(long long)n * 16 + j] = acc;
    }
}

// ------------- MLP2: out = relu((h+sum partials)@W2a+b2a)@W2b+b2b -----------
__global__ void mlp2_kernel(const float* __restrict__ h,
                            const float* __restrict__ partial, int S,
                            const float* __restrict__ W1, const float* __restrict__ b1,
                            const float* __restrict__ W2, const float* __restrict__ b2,
                            float* __restrict__ out, int N) {
    int n = blockIdx.x * blockDim.x + threadIdx.x;
    if (n >= N) return;
    float in[16];
    {
        const float4* p = (const float4*)(h + (long long)n * 16);
#pragma unroll
        for (int q = 0; q < 4; ++q) {
            float4 v = p[q];
            in[q * 4 + 0] = v.x; in[q * 4 + 1] = v.y;
            in[q * 4 + 2] = v.z; in[q * 4 + 3] = v.w;
        }
    }
    for (int s = 0; s < S; ++s) {
        const float4* p = (const float4*)(partial + (long long)s * N * 16 + (long long)n * 16);
#pragma unroll
        for (int q = 0; q < 4; ++q) {
            float4 v = p[q];
            in[q * 4 + 0] += v.x; in[q * 4 + 1] += v.y;
            in[q * 4 + 2] += v.z; in[q * 4 + 3] += v.w;
        }
    }
    float hid[16];
#pragma unroll
    for (int j = 0; j < 16; ++j) {
        float acc = b1[j];
#pragma unroll
        for (int f = 0; f < 16; ++f) acc = fmaf(in[f], W1[f * 16 + j], acc);
        hid[j] = fmaxf(acc, 0.0f);
    }
#pragma unroll
    for (int j = 0; j < 16; ++j) {
        float acc = b2[j];
#pragma unroll
        for (int k = 0; k < 16; ++k) acc = fmaf(hid[k], W2[k * 16 + j], acc);
        out[(long long)n * 16 + j] = acc;
    }
}

extern "C" void kernel_launch(void* const* d_in, const int* in_sizes, int n_in,
                              void* d_out, int out_size, void* d_ws, size_t ws_size,
                              hipStream_t stream) {
    const float* x    = (const float*)d_in[0];
    const void*  eidx = d_in[1];
    const float* W1a  = (const float*)d_in[2];
    const float* b1a  = (const float*)d_in[3];
    const float* W1b  = (const float*)d_in[4];
    const float* b1b  = (const float*)d_in[5];
    const float* W2a  = (const float*)d_in[6];
    const float* b2a  = (const float*)d_in[7];
    const float* W2b  = (const float*)d_in[8];
    const float* b2b  = (const float*)d_in[9];
    float* out = (float*)d_out;

    const int E = in_sizes[1] / 2;
    const int N = N_NODES;

    char* ws = (char*)d_ws;
    // workspace layout
    const size_t off_flag     = 0;
    const size_t off_binstart = 256;                               // (NBINS+1)*4
    const size_t off_hist     = 1024;                              // NCHUNK*NBINS*4 = 114688
    const size_t off_offrel   = off_hist + 114688;
    const size_t off_sorted   = off_offrel + 114688;               // E*4
    const size_t off_h        = (off_sorted + (size_t)E * 4 + 255) & ~(size_t)255;
    const size_t off_p1       = off_h + (size_t)N * 16 * 4;
    const size_t per_S_bytes  = (size_t)N * 5 * 4 + (size_t)N * 16 * 4;  // 8.4 MB

    unsigned int* flag = (unsigned int*)(ws + off_flag);
    int S = 0;
    if (ws_size > off_p1) S = (int)((ws_size - off_p1) / per_S_bytes);
    if (S > 8) S = 8;

    if (S >= 1) {
        int* bin_start      = (int*)(ws + off_binstart);
        int* hist           = (int*)(ws + off_hist);
        int* off_rel        = (int*)(ws + off_offrel);
        unsigned int* sorted= (unsigned int*)(ws + off_sorted);
        float* h            = (float*)(ws + off_h);
        float* p1           = (float*)(ws + off_p1);
        float* p2           = (float*)(ws + off_p1 + (size_t)S * N * 5 * 4);

        hipMemsetAsync(ws, 0, 4, stream);
        detect_i64_kernel<<<8, 256, 0, stream>>>((const unsigned int*)eidx, flag);
        count_kernel<<<NCHUNK, 256, 0, stream>>>(eidx, flag, hist, E);
        scan_kernel<<<1, 1024, 0, stream>>>(hist, off_rel, bin_start);
        scatter_kernel<<<NCHUNK, 256, 0, stream>>>(eidx, flag, off_rel, bin_start, sorted, E);

        dim3 agrid(S, NBINS);
        agg5_kernel<<<agrid, 1024, 0, stream>>>(sorted, bin_start, x, p1, S, N);
        mlp1_kernel<<<(N + 255) / 256, 256, 0, stream>>>(x, p1, S, W1a, b1a, W1b, b1b, h, N);
        agg16_kernel<<<agrid, 1024, 0, stream>>>(sorted, bin_start, h, p2, S, N);
        mlp2_kernel<<<(N + 255) / 256, 256, 0, stream>>>(h, p2, S, W2a, b2a, W2b, b2b, out, N);
    } else {
        // fallback: global-atomic path (round-1 behavior)
        const size_t f_agg1 = 4096;
        const size_t f_agg2 = f_agg1 + 2 * 1024 * 1024;
        const size_t f_h    = f_agg2 + 7 * 1024 * 1024;
        float* agg1 = (float*)(ws + f_agg1);
        float* agg2 = (float*)(ws + f_agg2);
        float* h    = (float*)(ws + f_h);

        hipMemsetAsync(ws, 0, f_agg2 + (size_t)N * 16 * 4, stream);
        detect_i64_kernel<<<8, 256, 0, stream>>>((const unsigned int*)eidx, flag);
        int blocks = (E + 255) / 256;
        scatter_f5_kernel<<<blocks, 256, 0, stream>>>(eidx, flag, x, agg1, E);
        mlp1_kernel<<<(N + 255) / 256, 256, 0, stream>>>(x, agg1, 1, W1a, b1a, W1b, b1b, h, N);
        scatter_f16_kernel<<<blocks, 256, 0, stream>>>(eidx, flag, h, agg2, E);
        mlp2_kernel<<<(N + 255) / 256, 256, 0, stream>>>(h, agg2, 1, W2a, b2a, W2b, b2b, out, N);
    }
}

// Round 3
// 848.117 us; speedup vs baseline: 7.9637x; 1.0570x over previous
//
#include <hip/hip_runtime.h>

#define N_NODES   100000
#define BIN_NODES 1024
#define NBINS     98          // ceil(100000/1024)
#define NCHUNK    512
#define PS16      17          // padded LDS stride for F=16 (bank spread)
#define NSPLIT    5           // blocks per bin -> 490 blocks = one resident round

// ---------------- dtype detection ----------------
// edge_index values < 2^31. If int64 LE, every odd 32-bit word is 0.
__global__ void detect_i64_kernel(const unsigned int* __restrict__ e,
                                  unsigned int* __restrict__ flag) {
    int i = blockIdx.x * blockDim.x + threadIdx.x;  // 0..2047
    unsigned int v = e[2 * i + 1];
    if (v != 0u) atomicOr(flag, 1u);
}

// ---------------- pass 1: per-chunk histogram over dst bins ----------------
__global__ void count_kernel(const void* __restrict__ eidx,
                             const unsigned int* __restrict__ flag,
                             int* __restrict__ hist, int E) {
    __shared__ int lh[NBINS];
    int tid = threadIdx.x, c = blockIdx.x;
    for (int i = tid; i < NBINS; i += blockDim.x) lh[i] = 0;
    __syncthreads();
    int per = (E + NCHUNK - 1) / NCHUNK;
    int e0 = c * per, e1 = min(E, e0 + per);
    unsigned int is32 = *flag;
    for (int e = e0 + tid; e < e1; e += blockDim.x) {
        int d = is32 ? ((const int*)eidx)[E + e]
                     : (int)((const long long*)eidx)[E + e];
        atomicAdd(&lh[d >> 10], 1);
    }
    __syncthreads();
    for (int i = tid; i < NBINS; i += blockDim.x) hist[c * NBINS + i] = lh[i];
}

// ---------------- pass 2: scan -> bin starts + per-(chunk,bin) offsets ------
__global__ void scan_kernel(const int* __restrict__ hist,
                            int* __restrict__ off_rel,
                            int* __restrict__ bin_start) {
    __shared__ int totals[NBINS];
    int tid = threadIdx.x, wave = tid >> 6, lane = tid & 63;
    for (int b = wave; b < NBINS; b += 16) {
        int carry = 0;
        for (int k = 0; k < NCHUNK; k += 64) {
            int v = hist[(k + lane) * NBINS + b];
            int s = v;
            for (int off = 1; off < 64; off <<= 1) {
                int t = __shfl_up(s, off);
                if (lane >= off) s += t;
            }
            off_rel[(k + lane) * NBINS + b] = carry + s - v;   // exclusive
            carry += __shfl(s, 63);
        }
        if (lane == 0) totals[b] = carry;
    }
    __syncthreads();
    if (tid == 0) {
        int acc = 0;
        for (int b = 0; b < NBINS; ++b) { bin_start[b] = acc; acc += totals[b]; }
        bin_start[NBINS] = acc;
    }
}

// ---------------- pass 3: scatter edges into bin-sorted order ---------------
// packed edge: (dst_local << 17) | src   (src < 2^17, dst_local < 1024)
__global__ void scatter_kernel(const void* __restrict__ eidx,
                               const unsigned int* __restrict__ flag,
                               const int* __restrict__ off_rel,
                               const int* __restrict__ bin_start,
                               unsigned int* __restrict__ sorted, int E) {
    __shared__ int lcnt[NBINS];
    __shared__ int lbase[NBINS];
    int tid = threadIdx.x, c = blockIdx.x;
    for (int i = tid; i < NBINS; i += blockDim.x) {
        lcnt[i] = 0;
        lbase[i] = bin_start[i] + off_rel[c * NBINS + i];
    }
    __syncthreads();
    int per = (E + NCHUNK - 1) / NCHUNK;
    int e0 = c * per, e1 = min(E, e0 + per);
    unsigned int is32 = *flag;
    for (int e = e0 + tid; e < e1; e += blockDim.x) {
        int s, d;
        if (is32) {
            const int* p = (const int*)eidx; s = p[e]; d = p[E + e];
        } else {
            const long long* p = (const long long*)eidx; s = (int)p[e]; d = (int)p[E + e];
        }
        int b = d >> 10;
        int dl = d & 1023;
        int pos = lbase[b] + atomicAdd(&lcnt[b], 1);
        sorted[pos] = ((unsigned int)dl << 17) | (unsigned int)s;
    }
}

// ---------------- aggregation, F=16 (layer 2): LDS bin accumulate -----------
// 4 lanes per edge, float4 gather -> 16 edges in flight per wave
__global__ __launch_bounds__(1024) void agg16_kernel(
    const unsigned int* __restrict__ sorted, const int* __restrict__ bin_start,
    const float* __restrict__ h, float* __restrict__ partial, int S, int N) {
    __shared__ float lagg[BIN_NODES * PS16];   // 69,632 B -> 2 blocks/CU
    int tid = threadIdx.x, s = blockIdx.x, bin = blockIdx.y;
    for (int i = tid; i < BIN_NODES * PS16; i += 1024) lagg[i] = 0.f;
    __syncthreads();
    int bs = bin_start[bin], be = bin_start[bin + 1];
    int cnt = be - bs, per = (cnt + S - 1) / S;
    int e0 = bs + s * per, e1 = min(be, e0 + per);
    int g = tid >> 2, q = tid & 3;            // 256 groups x 4 lanes
#pragma unroll 4
    for (int e = e0 + g; e < e1; e += 256) {
        unsigned int p = sorted[e];
        int src = (int)(p & 0x1FFFF), dl = (int)(p >> 17);
        float4 v = *(const float4*)(h + src * 16 + q * 4);
        float* d = &lagg[dl * PS16 + q * 4];
        atomicAdd(&d[0], v.x);
        atomicAdd(&d[1], v.y);
        atomicAdd(&d[2], v.z);
        atomicAdd(&d[3], v.w);
    }
    __syncthreads();
    int base = bin * BIN_NODES;
    int bn = min(BIN_NODES, N - base);
    float* out = partial + (long long)s * N * 16;
    for (int i = tid; i < bn * 16; i += 1024) {
        int node = i >> 4, ff = i & 15;
        out[(long long)(base + node) * 16 + ff] = lagg[node * PS16 + ff];
    }
}

// ---------------- aggregation, F=5 (layer 1) --------------------------------
__global__ __launch_bounds__(1024) void agg5_kernel(
    const unsigned int* __restrict__ sorted, const int* __restrict__ bin_start,
    const float* __restrict__ x, float* __restrict__ partial, int S, int N) {
    __shared__ float lagg[BIN_NODES * 5];     // 20,480 B
    int tid = threadIdx.x, s = blockIdx.x, bin = blockIdx.y;
    for (int i = tid; i < BIN_NODES * 5; i += 1024) lagg[i] = 0.f;
    __syncthreads();
    int bs = bin_start[bin], be = bin_start[bin + 1];
    int cnt = be - bs, per = (cnt + S - 1) / S;
    int e0 = bs + s * per, e1 = min(be, e0 + per);
#pragma unroll 4
    for (int e = e0 + tid; e < e1; e += 1024) {
        unsigned int p = sorted[e];
        int src = (int)(p & 0x1FFFF), dl = (int)(p >> 17);
        const float* xs = x + (long long)src * 5;
#pragma unroll
        for (int f = 0; f < 5; ++f) atomicAdd(&lagg[dl * 5 + f], xs[f]);
    }
    __syncthreads();
    int base = bin * BIN_NODES;
    int bn = min(BIN_NODES, N - base);
    float* out = partial + (long long)s * N * 5;
    for (int i = tid; i < bn * 5; i += 1024) out[(long long)base * 5 + i] = lagg[i];
}

// ---------- fallback atomic scatters (used only if ws too small) ------------
__device__ __forceinline__ void load_edge(const void* eidx, unsigned int is32,
                                          int i, int E, int& s, int& d) {
    if (is32 == 0u) {
        const long long* p = (const long long*)eidx;
        s = (int)p[i]; d = (int)p[E + i];
    } else {
        const int* p = (const int*)eidx;
        s = p[i]; d = p[E + i];
    }
}

__global__ void scatter_f5_kernel(const void* __restrict__ eidx,
                                  const unsigned int* __restrict__ flag,
                                  const float* __restrict__ x,
                                  float* __restrict__ agg, int E) {
    int i = blockIdx.x * blockDim.x + threadIdx.x;
    if (i >= E) return;
    int s, d; load_edge(eidx, *flag, i, E, s, d);
    const float* xs = x + (long long)s * 5;
    float* a = agg + (long long)d * 5;
#pragma unroll
    for (int f = 0; f < 5; ++f) atomicAdd(&a[f], xs[f]);
}

__global__ void scatter_f16_kernel(const void* __restrict__ eidx,
                                   const unsigned int* __restrict__ flag,
                                   const float* __restrict__ h,
                                   float* __restrict__ agg, int E) {
    int i = blockIdx.x * blockDim.x + threadIdx.x;
    if (i >= E) return;
    int s, d; load_edge(eidx, *flag, i, E, s, d);
    const float* hs = h + (long long)s * 16;
    float* a = agg + (long long)d * 16;
#pragma unroll
    for (int f = 0; f < 16; ++f) atomicAdd(&a[f], hs[f]);
}

// ------------- MLP1: h = relu((x+sum partials)@W1a+b1a)@W1b+b1b -------------
__global__ void mlp1_kernel(const float* __restrict__ x,
                            const float* __restrict__ partial, int S,
                            const float* __restrict__ W1, const float* __restrict__ b1,
                            const float* __restrict__ W2, const float* __restrict__ b2,
                            float* __restrict__ out, int N) {
    int n = blockIdx.x * blockDim.x + threadIdx.x;
    if (n >= N) return;
    float in[5];
#pragma unroll
    for (int f = 0; f < 5; ++f) in[f] = x[(long long)n * 5 + f];
    for (int s = 0; s < S; ++s) {
        const float* p = partial + (long long)s * N * 5 + (long long)n * 5;
#pragma unroll
        for (int f = 0; f < 5; ++f) in[f] += p[f];
    }
    float hid[16];
#pragma unroll
    for (int j = 0; j < 16; ++j) {
        float acc = b1[j];
#pragma unroll
        for (int f = 0; f < 5; ++f) acc = fmaf(in[f], W1[f * 16 + j], acc);
        hid[j] = fmaxf(acc, 0.0f);
    }
#pragma unroll
    for (int j = 0; j < 16; ++j) {
        float acc = b2[j];
#pragma unroll
        for (int k = 0; k < 16; ++k) acc = fmaf(hid[k], W2[k * 16 + j], acc);
        out[(long long)n * 16 + j] = acc;
    }
}

// ------------- MLP2: out = relu((h+sum partials)@W2a+b2a)@W2b+b2b -----------
__global__ void mlp2_kernel(const float* __restrict__ h,
                            const float* __restrict__ partial, int S,
                            const float* __restrict__ W1, const float* __restrict__ b1,
                            const float* __restrict__ W2, const float* __restrict__ b2,
                            float* __restrict__ out, int N) {
    int n = blockIdx.x * blockDim.x + threadIdx.x;
    if (n >= N) return;
    float in[16];
    {
        const float4* p = (const float4*)(h + (long long)n * 16);
#pragma unroll
        for (int q = 0; q < 4; ++q) {
            float4 v = p[q];
            in[q * 4 + 0] = v.x; in[q * 4 + 1] = v.y;
            in[q * 4 + 2] = v.z; in[q * 4 + 3] = v.w;
        }
    }
    for (int s = 0; s < S; ++s) {
        const float4* p = (const float4*)(partial + (long long)s * N * 16 + (long long)n * 16);
#pragma unroll
        for (int q = 0; q < 4; ++q) {
            float4 v = p[q];
            in[q * 4 + 0] += v.x; in[q * 4 + 1] += v.y;
            in[q * 4 + 2] += v.z; in[q * 4 + 3] += v.w;
        }
    }
    float hid[16];
#pragma unroll
    for (int j = 0; j < 16; ++j) {
        float acc = b1[j];
#pragma unroll
        for (int f = 0; f < 16; ++f) acc = fmaf(in[f], W1[f * 16 + j], acc);
        hid[j] = fmaxf(acc, 0.0f);
    }
#pragma unroll
    for (int j = 0; j < 16; ++j) {
        float acc = b2[j];
#pragma unroll
        for (int k = 0; k < 16; ++k) acc = fmaf(hid[k], W2[k * 16 + j], acc);
        out[(long long)n * 16 + j] = acc;
    }
}

extern "C" void kernel_launch(void* const* d_in, const int* in_sizes, int n_in,
                              void* d_out, int out_size, void* d_ws, size_t ws_size,
                              hipStream_t stream) {
    const float* x    = (const float*)d_in[0];
    const void*  eidx = d_in[1];
    const float* W1a  = (const float*)d_in[2];
    const float* b1a  = (const float*)d_in[3];
    const float* W1b  = (const float*)d_in[4];
    const float* b1b  = (const float*)d_in[5];
    const float* W2a  = (const float*)d_in[6];
    const float* b2a  = (const float*)d_in[7];
    const float* W2b  = (const float*)d_in[8];
    const float* b2b  = (const float*)d_in[9];
    float* out = (float*)d_out;

    const int E = in_sizes[1] / 2;
    const int N = N_NODES;

    char* ws = (char*)d_ws;
    // workspace layout
    const size_t off_flag     = 0;
    const size_t off_binstart = 256;                               // (NBINS+1)*4
    const size_t hist_bytes   = (size_t)NCHUNK * NBINS * 4;        // 200,704
    const size_t off_hist     = 1024;
    const size_t off_offrel   = off_hist + hist_bytes;
    const size_t off_sorted   = off_offrel + hist_bytes;           // E*4
    const size_t off_h        = (off_sorted + (size_t)E * 4 + 255) & ~(size_t)255;
    const size_t off_p1       = off_h + (size_t)N * 16 * 4;
    const size_t per_S_bytes  = (size_t)N * 5 * 4 + (size_t)N * 16 * 4;  // 8.4 MB

    unsigned int* flag = (unsigned int*)(ws + off_flag);
    int S = 0;
    if (ws_size > off_p1) S = (int)((ws_size - off_p1) / per_S_bytes);
    if (S > NSPLIT) S = NSPLIT;

    if (S >= 1) {
        int* bin_start      = (int*)(ws + off_binstart);
        int* hist           = (int*)(ws + off_hist);
        int* off_rel        = (int*)(ws + off_offrel);
        unsigned int* sorted= (unsigned int*)(ws + off_sorted);
        float* h            = (float*)(ws + off_h);
        float* p1           = (float*)(ws + off_p1);
        float* p2           = (float*)(ws + off_p1 + (size_t)S * N * 5 * 4);

        hipMemsetAsync(ws, 0, 4, stream);
        detect_i64_kernel<<<8, 256, 0, stream>>>((const unsigned int*)eidx, flag);
        count_kernel<<<NCHUNK, 256, 0, stream>>>(eidx, flag, hist, E);
        scan_kernel<<<1, 1024, 0, stream>>>(hist, off_rel, bin_start);
        scatter_kernel<<<NCHUNK, 256, 0, stream>>>(eidx, flag, off_rel, bin_start, sorted, E);

        dim3 agrid(S, NBINS);
        agg5_kernel<<<agrid, 1024, 0, stream>>>(sorted, bin_start, x, p1, S, N);
        mlp1_kernel<<<(N + 255) / 256, 256, 0, stream>>>(x, p1, S, W1a, b1a, W1b, b1b, h, N);
        agg16_kernel<<<agrid, 1024, 0, stream>>>(sorted, bin_start, h, p2, S, N);
        mlp2_kernel<<<(N + 255) / 256, 256, 0, stream>>>(h, p2, S, W2a, b2a, W2b, b2b, out, N);
    } else {
        // fallback: global-atomic path (round-1 behavior)
        const size_t f_agg1 = 4096;
        const size_t f_agg2 = f_agg1 + 2 * 1024 * 1024;
        const size_t f_h    = f_agg2 + 7 * 1024 * 1024;
        float* agg1 = (float*)(ws + f_agg1);
        float* agg2 = (float*)(ws + f_agg2);
        float* h    = (float*)(ws + f_h);

        hipMemsetAsync(ws, 0, f_agg2 + (size_t)N * 16 * 4, stream);
        detect_i64_kernel<<<8, 256, 0, stream>>>((const unsigned int*)eidx, flag);
        int blocks = (E + 255) / 256;
        scatter_f5_kernel<<<blocks, 256, 0, stream>>>(eidx, flag, x, agg1, E);
        mlp1_kernel<<<(N + 255) / 256, 256, 0, stream>>>(x, agg1, 1, W1a, b1a, W1b, b1b, h, N);
        scatter_f16_kernel<<<blocks, 256, 0, stream>>>(eidx, flag, h, agg2, E);
        mlp2_kernel<<<(N + 255) / 256, 256, 0, stream>>>(h, agg2, 1, W2a, b2a, W2b, b2b, out, N);
    }
}